// Round 1
// baseline (3628.669 us; speedup 1.0000x reference)
//
#include <hip/hip_runtime.h>

#define N_NODES  50000
#define N_EDGES  800000
#define N_GRAPHS 64

// ---------------- utility kernels ----------------

__global__ void zero_kernel(float* __restrict__ p, int n) {
    for (int i = blockIdx.x * blockDim.x + threadIdx.x; i < n; i += gridDim.x * blockDim.x)
        p[i] = 0.f;
}

__global__ void degree_kernel(const int* __restrict__ ei, float* __restrict__ deg) {
    const int* dst = ei + N_EDGES;
    for (int e = blockIdx.x * blockDim.x + threadIdx.x; e < N_EDGES; e += gridDim.x * blockDim.x)
        atomicAdd(&deg[dst[e]], 1.f);
}

__global__ void dinv_kernel(float* __restrict__ deg) {
    for (int i = blockIdx.x * blockDim.x + threadIdx.x; i < N_NODES; i += gridDim.x * blockDim.x)
        deg[i] = rsqrtf(deg[i] + 1.f);   // deg includes self-loop
}

// ---------------- GEMM: C[M,128] = A[M,K] @ B[K,128], fp32 ----------------
// BM=64, BN=128, BK=16; 256 threads; thread tile 8 rows x 4 cols.
template<int K>
__global__ __launch_bounds__(256) void gemm_n128(const float* __restrict__ A,
                                                 const float* __restrict__ B,
                                                 float* __restrict__ C, int M) {
    constexpr int BK = 16;
    __shared__ float As[BK][68];    // transposed: As[k][row], pad to 68 (16B-aligned rows)
    __shared__ float Bs[BK][132];   // Bs[k][col], pad to 132

    const int tid = threadIdx.x;
    const int tx  = tid & 31;   // col group: cols tx*4 .. tx*4+3
    const int ty  = tid >> 5;   // row group: rows ty*8 .. ty*8+7
    const int row0 = blockIdx.x * 64;

    // global load mapping
    const int lar = tid >> 2;          // A tile row 0..63
    const int lak = (tid & 3) * 4;     // A tile k offset 0,4,8,12
    const int lbk = tid >> 4;          // B tile k row 0..15
    const int lbc = (tid & 15) * 8;    // B tile col offset

    float acc[8][4];
    #pragma unroll
    for (int i = 0; i < 8; ++i)
        #pragma unroll
        for (int j = 0; j < 4; ++j) acc[i][j] = 0.f;

    int arow = row0 + lar;
    if (arow >= M) arow = M - 1;       // clamp: loaded values unused on store
    const float* Aptr = A + (long)arow * K + lak;
    const float* Bptr = B + (long)lbk * 128 + lbc;

    for (int k0 = 0; k0 < K; k0 += BK) {
        float4 av = *(const float4*)(Aptr + k0);
        As[lak + 0][lar] = av.x;
        As[lak + 1][lar] = av.y;
        As[lak + 2][lar] = av.z;
        As[lak + 3][lar] = av.w;
        float4 bv0 = *(const float4*)(Bptr + (long)k0 * 128);
        float4 bv1 = *(const float4*)(Bptr + (long)k0 * 128 + 4);
        *(float4*)&Bs[lbk][lbc]     = bv0;
        *(float4*)&Bs[lbk][lbc + 4] = bv1;
        __syncthreads();
        #pragma unroll
        for (int kk = 0; kk < BK; ++kk) {
            float4 b4 = *(const float4*)&Bs[kk][tx * 4];
            float4 a0 = *(const float4*)&As[kk][ty * 8];
            float4 a1 = *(const float4*)&As[kk][ty * 8 + 4];
            float a[8] = {a0.x, a0.y, a0.z, a0.w, a1.x, a1.y, a1.z, a1.w};
            float b[4] = {b4.x, b4.y, b4.z, b4.w};
            #pragma unroll
            for (int i = 0; i < 8; ++i)
                #pragma unroll
                for (int j = 0; j < 4; ++j)
                    acc[i][j] = fmaf(a[i], b[j], acc[i][j]);
        }
        __syncthreads();
    }

    #pragma unroll
    for (int i = 0; i < 8; ++i) {
        int r = row0 + ty * 8 + i;
        if (r < M) {
            float4 v = make_float4(acc[i][0], acc[i][1], acc[i][2], acc[i][3]);
            *(float4*)(C + (long)r * 128 + tx * 4) = v;
        }
    }
}

// ---------------- aggregation ----------------

// agg[i,c] = dinv[i]^2 * xl[i,c]   (self-loop term doubles as zero-init)
__global__ void init_agg_kernel(const float* __restrict__ xl, const float* __restrict__ dinv,
                                float* __restrict__ agg) {
    const int n4 = N_NODES * 32;
    for (int i = blockIdx.x * blockDim.x + threadIdx.x; i < n4; i += gridDim.x * blockDim.x) {
        int row = i >> 5;
        float di = dinv[row];
        float w = di * di;
        float4 v = ((const float4*)xl)[i];
        ((float4*)agg)[i] = make_float4(w * v.x, w * v.y, w * v.z, w * v.w);
    }
}

// agg[dst] += dinv[src]*dinv[dst] * xl[src]  over all edges
__global__ void scatter_kernel(const float* __restrict__ xl, const float* __restrict__ dinv,
                               const int* __restrict__ ei, float* __restrict__ agg) {
    const int* src = ei;
    const int* dst = ei + N_EDGES;
    const int lane = threadIdx.x & 31;  // channel quad c = lane*4
    const int eo   = threadIdx.x >> 5;  // 8 edges per block-iter
    for (int e = blockIdx.x * 8 + eo; e < N_EDGES; e += gridDim.x * 8) {
        int s = src[e], d = dst[e];
        float w = dinv[s] * dinv[d];
        float4 v = *(const float4*)(xl + (long)s * 128 + lane * 4);
        float* outp = agg + (long)d * 128 + lane * 4;
        atomicAdd(outp + 0, w * v.x);
        atomicAdd(outp + 1, w * v.y);
        atomicAdd(outp + 2, w * v.z);
        atomicAdd(outp + 3, w * v.w);
    }
}

// h = relu(agg + b), in place
__global__ void bias_relu_kernel(float* __restrict__ agg, const float* __restrict__ b) {
    const int n4 = N_NODES * 32;
    for (int i = blockIdx.x * blockDim.x + threadIdx.x; i < n4; i += gridDim.x * blockDim.x) {
        int c4 = i & 31;
        float4 bb = ((const float4*)b)[c4];
        float4 v = ((float4*)agg)[i];
        v.x = fmaxf(v.x + bb.x, 0.f);
        v.y = fmaxf(v.y + bb.y, 0.f);
        v.z = fmaxf(v.z + bb.z, 0.f);
        v.w = fmaxf(v.w + bb.w, 0.f);
        ((float4*)agg)[i] = v;
    }
}

// per node: z = dot(relu(agg2+b2), Wl); zsum[batch] += z; cnt[batch] += 1
__global__ void pool_kernel(const float* __restrict__ agg2, const float* __restrict__ b2,
                            const float* __restrict__ Wl, const int* __restrict__ batch,
                            float* __restrict__ zsum, float* __restrict__ cnt) {
    int node = blockIdx.x * 2 + (threadIdx.x >> 7);
    int c = threadIdx.x & 127;
    float v = agg2[(long)node * 128 + c] + b2[c];
    v = fmaxf(v, 0.f) * Wl[c];
    #pragma unroll
    for (int off = 32; off > 0; off >>= 1)
        v += __shfl_down(v, off);
    if ((threadIdx.x & 63) == 0) {
        int g = batch[node];
        atomicAdd(&zsum[g], v);
        if (c == 0) atomicAdd(&cnt[g], 1.f);
    }
}

__global__ void out_kernel(const float* __restrict__ zsum, const float* __restrict__ cnt,
                           const float* __restrict__ bl, float* __restrict__ out) {
    int g = threadIdx.x;
    if (g < N_GRAPHS) out[g] = zsum[g] / fmaxf(cnt[g], 1.f) + bl[0];
}

// ---------------- launch ----------------

extern "C" void kernel_launch(void* const* d_in, const int* in_sizes, int n_in,
                              void* d_out, int out_size, void* d_ws, size_t ws_size,
                              hipStream_t stream) {
    const float* x    = (const float*)d_in[0];
    const int*   ei   = (const int*)d_in[1];
    const int*   batch= (const int*)d_in[2];
    const float* W1   = (const float*)d_in[3];
    const float* b1   = (const float*)d_in[4];
    const float* W2   = (const float*)d_in[5];
    const float* b2   = (const float*)d_in[6];
    const float* Wl   = (const float*)d_in[7];
    const float* bl   = (const float*)d_in[8];
    float* out = (float*)d_out;

    float* ws   = (float*)d_ws;
    float* dinv = ws;                  // 50000
    float* zsum = ws + 50000;          // 64
    float* cnt  = ws + 50064;          // 64
    float* bufA = ws + 50176;          // 6.4M floats (xl1, then xl2)
    float* bufB = bufA + 6400000;      // 6.4M floats (agg1/h1, then agg2)

    zero_kernel<<<128, 256, 0, stream>>>(ws, 50128);
    degree_kernel<<<1024, 256, 0, stream>>>(ei, dinv);
    dinv_kernel<<<128, 256, 0, stream>>>(dinv);

    // layer 1: h1 = relu(GCNConv(x; W1) + b1)
    gemm_n128<768><<<782, 256, 0, stream>>>(x, W1, bufA, N_NODES);
    init_agg_kernel<<<2048, 256, 0, stream>>>(bufA, dinv, bufB);
    scatter_kernel<<<4096, 256, 0, stream>>>(bufA, dinv, ei, bufB);
    bias_relu_kernel<<<2048, 256, 0, stream>>>(bufB, b1);

    // layer 2: agg2 (pre-bias/relu) left in bufB
    gemm_n128<128><<<782, 256, 0, stream>>>(bufB, W2, bufA, N_NODES);
    init_agg_kernel<<<2048, 256, 0, stream>>>(bufA, dinv, bufB);
    scatter_kernel<<<4096, 256, 0, stream>>>(bufA, dinv, ei, bufB);

    // pooled mean + final linear (Wl folded per node)
    pool_kernel<<<25000, 256, 0, stream>>>(bufB, b2, Wl, batch, zsum, cnt);
    out_kernel<<<1, 64, 0, stream>>>(zsum, cnt, bl, out);
}

// Round 2
// 1188.790 us; speedup vs baseline: 3.0524x; 3.0524x over previous
//
#include <hip/hip_runtime.h>

#define N_NODES  50000
#define N_EDGES  800000
#define N_GRAPHS 64

// ---------------- utility kernels ----------------

__global__ void zero_int_kernel(int* __restrict__ p, int n) {
    for (int i = blockIdx.x * blockDim.x + threadIdx.x; i < n; i += gridDim.x * blockDim.x)
        p[i] = 0;
}

// in-degree histogram (int)
__global__ void hist_kernel(const int* __restrict__ ei, int* __restrict__ cnt) {
    const int* dst = ei + N_EDGES;
    for (int e = blockIdx.x * blockDim.x + threadIdx.x; e < N_EDGES; e += gridDim.x * blockDim.x)
        atomicAdd(&cnt[dst[e]], 1);
}

__global__ void dinv_kernel(const int* __restrict__ cnt, float* __restrict__ dinv) {
    for (int i = blockIdx.x * blockDim.x + threadIdx.x; i < N_NODES; i += gridDim.x * blockDim.x)
        dinv[i] = rsqrtf((float)cnt[i] + 1.f);   // +1 self-loop
}

// single-block exclusive scan of cnt -> rowptr; also resets cnt to 0 (fill counters)
__global__ __launch_bounds__(1024) void scan_kernel(int* __restrict__ cnt, int* __restrict__ rowptr) {
    __shared__ int part[1024];
    const int CH = 49;                      // 1024*49 = 50176 >= N_NODES
    int t = threadIdx.x;
    int base = t * CH;
    int s = 0;
    for (int i = 0; i < CH; ++i) {
        int idx = base + i;
        if (idx < N_NODES) s += cnt[idx];
    }
    part[t] = s;
    __syncthreads();
    for (int off = 1; off < 1024; off <<= 1) {
        int v = (t >= off) ? part[t - off] : 0;
        __syncthreads();
        part[t] += v;
        __syncthreads();
    }
    int run = (t == 0) ? 0 : part[t - 1];
    for (int i = 0; i < CH; ++i) {
        int idx = base + i;
        if (idx < N_NODES) {
            int c = cnt[idx];
            rowptr[idx] = run;
            run += c;
            cnt[idx] = 0;                   // reset for fill pass
        }
    }
    if (t == 1023) rowptr[N_NODES] = run;
}

// place edges into CSR slots
__global__ void fill_kernel(const int* __restrict__ ei, const int* __restrict__ rowptr,
                            int* __restrict__ fill, const float* __restrict__ dinv,
                            int* __restrict__ csr_src, float* __restrict__ csr_w) {
    const int* src = ei;
    const int* dst = ei + N_EDGES;
    for (int e = blockIdx.x * blockDim.x + threadIdx.x; e < N_EDGES; e += gridDim.x * blockDim.x) {
        int s = src[e], d = dst[e];
        int pos = rowptr[d] + atomicAdd(&fill[d], 1);
        csr_src[pos] = s;
        csr_w[pos] = dinv[s] * dinv[d];
    }
}

// nodes-per-graph histogram (float)
__global__ void gcount_kernel(const int* __restrict__ batch, float* __restrict__ cntg) {
    for (int i = blockIdx.x * blockDim.x + threadIdx.x; i < N_NODES; i += gridDim.x * blockDim.x)
        atomicAdd(&cntg[batch[i]], 1.f);
}

// ---------------- GEMM: C[M,128] = A[M,K] @ B[K,128], fp32 ----------------
template<int K>
__global__ __launch_bounds__(256) void gemm_n128(const float* __restrict__ A,
                                                 const float* __restrict__ B,
                                                 float* __restrict__ C, int M) {
    constexpr int BK = 16;
    __shared__ float As[BK][68];
    __shared__ float Bs[BK][132];

    const int tid = threadIdx.x;
    const int tx  = tid & 31;
    const int ty  = tid >> 5;
    const int row0 = blockIdx.x * 64;

    const int lar = tid >> 2;
    const int lak = (tid & 3) * 4;
    const int lbk = tid >> 4;
    const int lbc = (tid & 15) * 8;

    float acc[8][4];
    #pragma unroll
    for (int i = 0; i < 8; ++i)
        #pragma unroll
        for (int j = 0; j < 4; ++j) acc[i][j] = 0.f;

    int arow = row0 + lar;
    if (arow >= M) arow = M - 1;
    const float* Aptr = A + (long)arow * K + lak;
    const float* Bptr = B + (long)lbk * 128 + lbc;

    for (int k0 = 0; k0 < K; k0 += BK) {
        float4 av = *(const float4*)(Aptr + k0);
        As[lak + 0][lar] = av.x;
        As[lak + 1][lar] = av.y;
        As[lak + 2][lar] = av.z;
        As[lak + 3][lar] = av.w;
        float4 bv0 = *(const float4*)(Bptr + (long)k0 * 128);
        float4 bv1 = *(const float4*)(Bptr + (long)k0 * 128 + 4);
        *(float4*)&Bs[lbk][lbc]     = bv0;
        *(float4*)&Bs[lbk][lbc + 4] = bv1;
        __syncthreads();
        #pragma unroll
        for (int kk = 0; kk < BK; ++kk) {
            float4 b4 = *(const float4*)&Bs[kk][tx * 4];
            float4 a0 = *(const float4*)&As[kk][ty * 8];
            float4 a1 = *(const float4*)&As[kk][ty * 8 + 4];
            float a[8] = {a0.x, a0.y, a0.z, a0.w, a1.x, a1.y, a1.z, a1.w};
            float b[4] = {b4.x, b4.y, b4.z, b4.w};
            #pragma unroll
            for (int i = 0; i < 8; ++i)
                #pragma unroll
                for (int j = 0; j < 4; ++j)
                    acc[i][j] = fmaf(a[i], b[j], acc[i][j]);
        }
        __syncthreads();
    }

    #pragma unroll
    for (int i = 0; i < 8; ++i) {
        int r = row0 + ty * 8 + i;
        if (r < M) {
            float4 v = make_float4(acc[i][0], acc[i][1], acc[i][2], acc[i][3]);
            *(float4*)(C + (long)r * 128 + tx * 4) = v;
        }
    }
}

// ---------------- CSR gather: one wave per node, 2 channels per lane ----------------
// MODE 0: out[node] = relu(agg + bias)           (layer 1)
// MODE 1: z = dot(relu(agg + bias), Wl); zsum[batch[node]] += z   (layer 2 + pool)
template<int MODE>
__global__ __launch_bounds__(256) void gather_kernel(
        const float* __restrict__ xl, const float* __restrict__ dinv,
        const int* __restrict__ rowptr, const int* __restrict__ csr_src,
        const float* __restrict__ csr_w, const float* __restrict__ bias,
        float* __restrict__ outbuf,
        const float* __restrict__ Wl, const int* __restrict__ batch,
        float* __restrict__ zsum) {
    int node = blockIdx.x * 4 + (threadIdx.x >> 6);
    if (node >= N_NODES) return;
    int lane = threadIdx.x & 63;
    int c0 = lane * 2;

    float di = dinv[node];
    float2 v = *(const float2*)(xl + (long)node * 128 + c0);
    float acc0 = di * di * v.x;
    float acc1 = di * di * v.y;

    int e = rowptr[node];
    int end = rowptr[node + 1];
    for (; e + 1 < end; e += 2) {
        int s0 = csr_src[e], s1 = csr_src[e + 1];
        float w0 = csr_w[e], w1 = csr_w[e + 1];
        float2 u0 = *(const float2*)(xl + (long)s0 * 128 + c0);
        float2 u1 = *(const float2*)(xl + (long)s1 * 128 + c0);
        acc0 = fmaf(w0, u0.x, acc0);
        acc1 = fmaf(w0, u0.y, acc1);
        acc0 = fmaf(w1, u1.x, acc0);
        acc1 = fmaf(w1, u1.y, acc1);
    }
    if (e < end) {
        int s0 = csr_src[e];
        float w0 = csr_w[e];
        float2 u0 = *(const float2*)(xl + (long)s0 * 128 + c0);
        acc0 = fmaf(w0, u0.x, acc0);
        acc1 = fmaf(w0, u0.y, acc1);
    }

    float2 bb = *(const float2*)(bias + c0);
    acc0 = fmaxf(acc0 + bb.x, 0.f);
    acc1 = fmaxf(acc1 + bb.y, 0.f);

    if (MODE == 0) {
        *(float2*)(outbuf + (long)node * 128 + c0) = make_float2(acc0, acc1);
    } else {
        float2 wl = *(const float2*)(Wl + c0);
        float z = acc0 * wl.x + acc1 * wl.y;
        #pragma unroll
        for (int off = 32; off > 0; off >>= 1)
            z += __shfl_down(z, off);
        if (lane == 0)
            atomicAdd(&zsum[batch[node]], z);
    }
}

__global__ void out_kernel(const float* __restrict__ zsum, const float* __restrict__ cntg,
                           const float* __restrict__ bl, float* __restrict__ out) {
    int g = threadIdx.x;
    if (g < N_GRAPHS) out[g] = zsum[g] / fmaxf(cntg[g], 1.f) + bl[0];
}

// ---------------- launch ----------------

extern "C" void kernel_launch(void* const* d_in, const int* in_sizes, int n_in,
                              void* d_out, int out_size, void* d_ws, size_t ws_size,
                              hipStream_t stream) {
    const float* x    = (const float*)d_in[0];
    const int*   ei   = (const int*)d_in[1];
    const int*   batch= (const int*)d_in[2];
    const float* W1   = (const float*)d_in[3];
    const float* b1   = (const float*)d_in[4];
    const float* W2   = (const float*)d_in[5];
    const float* b2   = (const float*)d_in[6];
    const float* Wl   = (const float*)d_in[7];
    const float* bl   = (const float*)d_in[8];
    float* out = (float*)d_out;

    // workspace layout (floats/ints, 4B words)
    float* ws      = (float*)d_ws;
    float* dinv    = ws;                         // 50176
    float* zsum    = ws + 50176;                 // 64
    float* cntg    = ws + 50176 + 64;            // 64
    int*   cnt_i   = (int*)(ws + 50304);         // 50176 (also fill counters)
    int*   rowptr  = (int*)(ws + 100480);        // 50176 (50001 used)
    int*   csr_src = (int*)(ws + 150656);        // 800000
    float* csr_w   = ws + 950656;                // 800000
    float* bufA    = ws + 1750656;               // 6.4M
    float* bufB    = bufA + 6400000;             // 6.4M

    // zero zsum, cntg, cnt_i in one pass (contiguous: ws+50176 .. ws+100480)
    zero_int_kernel<<<128, 256, 0, stream>>>((int*)(ws + 50176), 128 + 50176);

    hist_kernel<<<1024, 256, 0, stream>>>(ei, cnt_i);
    dinv_kernel<<<128, 256, 0, stream>>>(cnt_i, dinv);
    scan_kernel<<<1, 1024, 0, stream>>>(cnt_i, rowptr);
    fill_kernel<<<1024, 256, 0, stream>>>(ei, rowptr, cnt_i, dinv, csr_src, csr_w);
    gcount_kernel<<<256, 256, 0, stream>>>(batch, cntg);

    // layer 1
    gemm_n128<768><<<782, 256, 0, stream>>>(x, W1, bufA, N_NODES);
    gather_kernel<0><<<12500, 256, 0, stream>>>(bufA, dinv, rowptr, csr_src, csr_w,
                                                b1, bufB, nullptr, nullptr, nullptr);
    // layer 2 + pool
    gemm_n128<128><<<782, 256, 0, stream>>>(bufB, W2, bufA, N_NODES);
    gather_kernel<1><<<12500, 256, 0, stream>>>(bufA, dinv, rowptr, csr_src, csr_w,
                                                b2, nullptr, Wl, batch, zsum);

    out_kernel<<<1, 64, 0, stream>>>(zsum, cntg, bl, out);
}

// Round 3
// 1131.252 us; speedup vs baseline: 3.2077x; 1.0509x over previous
//
#include <hip/hip_runtime.h>

#define N_NODES  50000
#define N_EDGES  800000
#define N_GRAPHS 64

// ---------------- utility kernels ----------------

__global__ void zero_int_kernel(int* __restrict__ p, int n) {
    for (int i = blockIdx.x * blockDim.x + threadIdx.x; i < n; i += gridDim.x * blockDim.x)
        p[i] = 0;
}

// in-degree histogram (int)
__global__ void hist_kernel(const int* __restrict__ ei, int* __restrict__ cnt) {
    const int* dst = ei + N_EDGES;
    for (int e = blockIdx.x * blockDim.x + threadIdx.x; e < N_EDGES; e += gridDim.x * blockDim.x)
        atomicAdd(&cnt[dst[e]], 1);
}

__global__ void dinv_kernel(const int* __restrict__ cnt, float* __restrict__ dinv) {
    for (int i = blockIdx.x * blockDim.x + threadIdx.x; i < N_NODES; i += gridDim.x * blockDim.x)
        dinv[i] = rsqrtf((float)cnt[i] + 1.f);   // +1 self-loop
}

// single-block exclusive scan of cnt -> rowptr; also resets cnt to 0 (fill counters)
__global__ __launch_bounds__(1024) void scan_kernel(int* __restrict__ cnt, int* __restrict__ rowptr) {
    __shared__ int part[1024];
    const int CH = 49;                      // 1024*49 = 50176 >= N_NODES
    int t = threadIdx.x;
    int base = t * CH;
    int s = 0;
    for (int i = 0; i < CH; ++i) {
        int idx = base + i;
        if (idx < N_NODES) s += cnt[idx];
    }
    part[t] = s;
    __syncthreads();
    for (int off = 1; off < 1024; off <<= 1) {
        int v = (t >= off) ? part[t - off] : 0;
        __syncthreads();
        part[t] += v;
        __syncthreads();
    }
    int run = (t == 0) ? 0 : part[t - 1];
    for (int i = 0; i < CH; ++i) {
        int idx = base + i;
        if (idx < N_NODES) {
            int c = cnt[idx];
            rowptr[idx] = run;
            run += c;
            cnt[idx] = 0;                   // reset for fill pass
        }
    }
    if (t == 1023) rowptr[N_NODES] = run;
}

// place edges into CSR slots; pack (src, weight) as int2
__global__ void fill_kernel(const int* __restrict__ ei, const int* __restrict__ rowptr,
                            int* __restrict__ fill, const float* __restrict__ dinv,
                            int2* __restrict__ csr) {
    const int* src = ei;
    const int* dst = ei + N_EDGES;
    for (int e = blockIdx.x * blockDim.x + threadIdx.x; e < N_EDGES; e += gridDim.x * blockDim.x) {
        int s = src[e], d = dst[e];
        int pos = rowptr[d] + atomicAdd(&fill[d], 1);
        csr[pos] = make_int2(s, __float_as_int(dinv[s] * dinv[d]));
    }
}

// nodes-per-graph histogram (float)
__global__ void gcount_kernel(const int* __restrict__ batch, float* __restrict__ cntg) {
    for (int i = blockIdx.x * blockDim.x + threadIdx.x; i < N_NODES; i += gridDim.x * blockDim.x)
        atomicAdd(&cntg[batch[i]], 1.f);
}

// ---------------- GEMM: C[M,128] = A[M,K] @ B[K,128], fp32 ----------------
template<int K>
__global__ __launch_bounds__(256) void gemm_n128(const float* __restrict__ A,
                                                 const float* __restrict__ B,
                                                 float* __restrict__ C, int M) {
    constexpr int BK = 16;
    __shared__ float As[BK][68];
    __shared__ float Bs[BK][132];

    const int tid = threadIdx.x;
    const int tx  = tid & 31;
    const int ty  = tid >> 5;
    const int row0 = blockIdx.x * 64;

    const int lar = tid >> 2;
    const int lak = (tid & 3) * 4;
    const int lbk = tid >> 4;
    const int lbc = (tid & 15) * 8;

    float acc[8][4];
    #pragma unroll
    for (int i = 0; i < 8; ++i)
        #pragma unroll
        for (int j = 0; j < 4; ++j) acc[i][j] = 0.f;

    int arow = row0 + lar;
    if (arow >= M) arow = M - 1;
    const float* Aptr = A + (long)arow * K + lak;
    const float* Bptr = B + (long)lbk * 128 + lbc;

    for (int k0 = 0; k0 < K; k0 += BK) {
        float4 av = *(const float4*)(Aptr + k0);
        As[lak + 0][lar] = av.x;
        As[lak + 1][lar] = av.y;
        As[lak + 2][lar] = av.z;
        As[lak + 3][lar] = av.w;
        float4 bv0 = *(const float4*)(Bptr + (long)k0 * 128);
        float4 bv1 = *(const float4*)(Bptr + (long)k0 * 128 + 4);
        *(float4*)&Bs[lbk][lbc]     = bv0;
        *(float4*)&Bs[lbk][lbc + 4] = bv1;
        __syncthreads();
        #pragma unroll
        for (int kk = 0; kk < BK; ++kk) {
            float4 b4 = *(const float4*)&Bs[kk][tx * 4];
            float4 a0 = *(const float4*)&As[kk][ty * 8];
            float4 a1 = *(const float4*)&As[kk][ty * 8 + 4];
            float a[8] = {a0.x, a0.y, a0.z, a0.w, a1.x, a1.y, a1.z, a1.w};
            float b[4] = {b4.x, b4.y, b4.z, b4.w};
            #pragma unroll
            for (int i = 0; i < 8; ++i)
                #pragma unroll
                for (int j = 0; j < 4; ++j)
                    acc[i][j] = fmaf(a[i], b[j], acc[i][j]);
        }
        __syncthreads();
    }

    #pragma unroll
    for (int i = 0; i < 8; ++i) {
        int r = row0 + ty * 8 + i;
        if (r < M) {
            float4 v = make_float4(acc[i][0], acc[i][1], acc[i][2], acc[i][3]);
            *(float4*)(C + (long)r * 128 + tx * 4) = v;
        }
    }
}

// ---------------- CSR gather: one wave per node ----------------
// Lane layout: es = lane>>4 (edge slot 0..3), cl = lane&15 (channel lane, 8 ch each).
// Unroll 2 -> 8 edges (8 independent 512B row reads) in flight per wave.
// MODE 0: out[node] = relu(agg + bias)
// MODE 1: z = dot(relu(agg + bias), Wl); zsum[batch[node]] += z
template<int MODE>
__global__ __launch_bounds__(256) void gather_kernel(
        const float* __restrict__ xl, const float* __restrict__ dinv,
        const int* __restrict__ rowptr, const int2* __restrict__ csr,
        const float* __restrict__ bias, float* __restrict__ outbuf,
        const float* __restrict__ Wl, const int* __restrict__ batch,
        float* __restrict__ zsum) {
    int node = blockIdx.x * 4 + (threadIdx.x >> 6);
    if (node >= N_NODES) return;
    const int lane = threadIdx.x & 63;
    const int es = lane >> 4;
    const int cl = lane & 15;
    const int c0 = cl * 8;

    const int start = rowptr[node];
    const int end   = rowptr[node + 1];

    // self-loop row (issue early; independent of loop)
    float di = dinv[node];
    float4 sl0 = *(const float4*)(xl + (long)node * 128 + c0);
    float4 sl1 = *(const float4*)(xl + (long)node * 128 + c0 + 4);

    float4 aA0 = {0,0,0,0}, aA1 = {0,0,0,0};
    float4 aB0 = {0,0,0,0}, aB1 = {0,0,0,0};

    for (int eb = start; eb < end; eb += 8) {
        int eA = eb + es;
        int eB = eA + 4;
        int eAc = (eA < end) ? eA : start;
        int eBc = (eB < end) ? eB : start;
        int2 cA = csr[eAc];
        int2 cB = csr[eBc];
        float wA = (eA < end) ? __int_as_float(cA.y) : 0.f;
        float wB = (eB < end) ? __int_as_float(cB.y) : 0.f;
        const float* rA = xl + (long)cA.x * 128 + c0;
        const float* rB = xl + (long)cB.x * 128 + c0;
        float4 uA0 = *(const float4*)(rA);
        float4 uA1 = *(const float4*)(rA + 4);
        float4 uB0 = *(const float4*)(rB);
        float4 uB1 = *(const float4*)(rB + 4);
        aA0.x = fmaf(wA, uA0.x, aA0.x); aA0.y = fmaf(wA, uA0.y, aA0.y);
        aA0.z = fmaf(wA, uA0.z, aA0.z); aA0.w = fmaf(wA, uA0.w, aA0.w);
        aA1.x = fmaf(wA, uA1.x, aA1.x); aA1.y = fmaf(wA, uA1.y, aA1.y);
        aA1.z = fmaf(wA, uA1.z, aA1.z); aA1.w = fmaf(wA, uA1.w, aA1.w);
        aB0.x = fmaf(wB, uB0.x, aB0.x); aB0.y = fmaf(wB, uB0.y, aB0.y);
        aB0.z = fmaf(wB, uB0.z, aB0.z); aB0.w = fmaf(wB, uB0.w, aB0.w);
        aB1.x = fmaf(wB, uB1.x, aB1.x); aB1.y = fmaf(wB, uB1.y, aB1.y);
        aB1.z = fmaf(wB, uB1.z, aB1.z); aB1.w = fmaf(wB, uB1.w, aB1.w);
    }

    // merge unroll legs
    float s[8];
    s[0] = aA0.x + aB0.x; s[1] = aA0.y + aB0.y; s[2] = aA0.z + aB0.z; s[3] = aA0.w + aB0.w;
    s[4] = aA1.x + aB1.x; s[5] = aA1.y + aB1.y; s[6] = aA1.z + aB1.z; s[7] = aA1.w + aB1.w;

    // reduce across the 4 edge slots (lanes cl, cl+16, cl+32, cl+48)
    #pragma unroll
    for (int i = 0; i < 8; ++i) {
        s[i] += __shfl_xor(s[i], 16);
        s[i] += __shfl_xor(s[i], 32);
    }

    // self-loop + bias + relu
    float w2 = di * di;
    float slv[8] = {sl0.x, sl0.y, sl0.z, sl0.w, sl1.x, sl1.y, sl1.z, sl1.w};
    const float4 bb0 = *(const float4*)(bias + c0);
    const float4 bb1 = *(const float4*)(bias + c0 + 4);
    float bv[8] = {bb0.x, bb0.y, bb0.z, bb0.w, bb1.x, bb1.y, bb1.z, bb1.w};
    #pragma unroll
    for (int i = 0; i < 8; ++i)
        s[i] = fmaxf(fmaf(w2, slv[i], s[i]) + bv[i], 0.f);

    if (MODE == 0) {
        if (es == 0) {
            float4 o0 = make_float4(s[0], s[1], s[2], s[3]);
            float4 o1 = make_float4(s[4], s[5], s[6], s[7]);
            *(float4*)(outbuf + (long)node * 128 + c0)     = o0;
            *(float4*)(outbuf + (long)node * 128 + c0 + 4) = o1;
        }
    } else {
        const float4 wl0 = *(const float4*)(Wl + c0);
        const float4 wl1 = *(const float4*)(Wl + c0 + 4);
        float z = s[0]*wl0.x + s[1]*wl0.y + s[2]*wl0.z + s[3]*wl0.w
                + s[4]*wl1.x + s[5]*wl1.y + s[6]*wl1.z + s[7]*wl1.w;
        z += __shfl_xor(z, 1);
        z += __shfl_xor(z, 2);
        z += __shfl_xor(z, 4);
        z += __shfl_xor(z, 8);
        if (lane == 0)
            atomicAdd(&zsum[batch[node]], z);
    }
}

__global__ void out_kernel(const float* __restrict__ zsum, const float* __restrict__ cntg,
                           const float* __restrict__ bl, float* __restrict__ out) {
    int g = threadIdx.x;
    if (g < N_GRAPHS) out[g] = zsum[g] / fmaxf(cntg[g], 1.f) + bl[0];
}

// ---------------- launch ----------------

extern "C" void kernel_launch(void* const* d_in, const int* in_sizes, int n_in,
                              void* d_out, int out_size, void* d_ws, size_t ws_size,
                              hipStream_t stream) {
    const float* x    = (const float*)d_in[0];
    const int*   ei   = (const int*)d_in[1];
    const int*   batch= (const int*)d_in[2];
    const float* W1   = (const float*)d_in[3];
    const float* b1   = (const float*)d_in[4];
    const float* W2   = (const float*)d_in[5];
    const float* b2   = (const float*)d_in[6];
    const float* Wl   = (const float*)d_in[7];
    const float* bl   = (const float*)d_in[8];
    float* out = (float*)d_out;

    // workspace layout (4B words)
    float* ws      = (float*)d_ws;
    float* dinv    = ws;                         // 50176
    float* zsum    = ws + 50176;                 // 64
    float* cntg    = ws + 50176 + 64;            // 64
    int*   cnt_i   = (int*)(ws + 50304);         // 50176 (also fill counters)
    int*   rowptr  = (int*)(ws + 100480);        // 50176 (50001 used)
    int2*  csr     = (int2*)(ws + 150656);       // 800000 int2 (8B-aligned offset)
    float* bufA    = ws + 1750656;               // 6.4M
    float* bufB    = bufA + 6400000;             // 6.4M

    // zero zsum, cntg, cnt_i in one pass (contiguous)
    zero_int_kernel<<<128, 256, 0, stream>>>((int*)(ws + 50176), 128 + 50176);

    hist_kernel<<<1024, 256, 0, stream>>>(ei, cnt_i);
    dinv_kernel<<<128, 256, 0, stream>>>(cnt_i, dinv);
    scan_kernel<<<1, 1024, 0, stream>>>(cnt_i, rowptr);
    fill_kernel<<<1024, 256, 0, stream>>>(ei, rowptr, cnt_i, dinv, csr);
    gcount_kernel<<<256, 256, 0, stream>>>(batch, cntg);

    // layer 1
    gemm_n128<768><<<782, 256, 0, stream>>>(x, W1, bufA, N_NODES);
    gather_kernel<0><<<12500, 256, 0, stream>>>(bufA, dinv, rowptr, csr,
                                                b1, bufB, nullptr, nullptr, nullptr);
    // layer 2 + pool
    gemm_n128<128><<<782, 256, 0, stream>>>(bufB, W2, bufA, N_NODES);
    gather_kernel<1><<<12500, 256, 0, stream>>>(bufA, dinv, rowptr, csr,
                                                b2, nullptr, Wl, batch, zsum);

    out_kernel<<<1, 64, 0, stream>>>(zsum, cntg, bl, out);
}